// Round 1
// baseline (472.251 us; speedup 1.0000x reference)
//
#include <hip/hip_runtime.h>
#include <math.h>

#define B_      2
#define L_      2048
#define DIM_    512
#define DINNER  1024
#define DTRANK  32
#define DSTATE  16
#define DCONV   4
#define BL      (B_ * L_)        // 4096
#define NCHUNK  32
#define CLEN    (L_ / NCHUNK)    // 64

// ---------------- LayerNorm: one wave per row ----------------
__global__ __launch_bounds__(64) void ln_kernel(
    const float* __restrict__ x, const float* __restrict__ g,
    const float* __restrict__ b, float* __restrict__ h) {
  int row = blockIdx.x;
  int lane = threadIdx.x;
  const float* xr = x + (size_t)row * DIM_;
  float v[8];
  float sum = 0.f;
#pragma unroll
  for (int i = 0; i < 8; i++) { v[i] = xr[lane + i * 64]; sum += v[i]; }
#pragma unroll
  for (int o = 32; o > 0; o >>= 1) sum += __shfl_xor(sum, o, 64);
  float mu = sum * (1.f / DIM_);
  float vs = 0.f;
#pragma unroll
  for (int i = 0; i < 8; i++) { float d = v[i] - mu; vs += d * d; }
#pragma unroll
  for (int o = 32; o > 0; o >>= 1) vs += __shfl_xor(vs, o, 64);
  float rstd = rsqrtf(vs * (1.f / DIM_) + 1e-5f);
  float* hr = h + (size_t)row * DIM_;
#pragma unroll
  for (int i = 0; i < 8; i++) {
    int c = lane + i * 64;
    hr[c] = (v[i] - mu) * rstd * g[c] + b[c];
  }
}

// ---------------- fp32 tiled GEMM: C[M,N] = A[M,K] * B[N,K]^T (+Res) ------
// 64x64 tile, 256 threads, 4x4 microtile, K-tile 16.
template <bool ADD_RES>
__global__ __launch_bounds__(256) void gemm_tnt(
    const float* __restrict__ A, int lda,
    const float* __restrict__ Bw, int ldb,
    const float* __restrict__ Res, int ldr,
    float* __restrict__ C, int ldc, int K) {
  __shared__ float As[16][68];
  __shared__ float Bs[16][68];
  int t = threadIdx.x;
  int tx = t & 15, ty = t >> 4;
  int n0 = blockIdx.x * 64, m0 = blockIdx.y * 64;
  int lm = t >> 2;           // 0..63
  int lk = (t & 3) * 4;      // 0,4,8,12
  float acc[4][4] = {};
  const float* Ap = A + (size_t)(m0 + lm) * lda + lk;
  const float* Bp = Bw + (size_t)(n0 + lm) * ldb + lk;
  for (int k0 = 0; k0 < K; k0 += 16) {
    float4 a4 = *(const float4*)(Ap + k0);
    float4 b4 = *(const float4*)(Bp + k0);
    __syncthreads();
    As[lk + 0][lm] = a4.x; As[lk + 1][lm] = a4.y;
    As[lk + 2][lm] = a4.z; As[lk + 3][lm] = a4.w;
    Bs[lk + 0][lm] = b4.x; Bs[lk + 1][lm] = b4.y;
    Bs[lk + 2][lm] = b4.z; Bs[lk + 3][lm] = b4.w;
    __syncthreads();
#pragma unroll
    for (int kk = 0; kk < 16; kk++) {
      float4 a = *(const float4*)&As[kk][ty * 4];
      float4 bb = *(const float4*)&Bs[kk][tx * 4];
      float av[4] = {a.x, a.y, a.z, a.w};
      float bv[4] = {bb.x, bb.y, bb.z, bb.w};
#pragma unroll
      for (int i = 0; i < 4; i++)
#pragma unroll
        for (int j = 0; j < 4; j++) acc[i][j] += av[i] * bv[j];
    }
  }
#pragma unroll
  for (int i = 0; i < 4; i++) {
    int m = m0 + ty * 4 + i;
    float4 o;
    o.x = acc[i][0]; o.y = acc[i][1]; o.z = acc[i][2]; o.w = acc[i][3];
    if (ADD_RES) {
      float4 r = *(const float4*)(Res + (size_t)m * ldr + n0 + tx * 4);
      o.x += r.x; o.y += r.y; o.z += r.z; o.w += r.w;
    }
    *(float4*)(C + (size_t)m * ldc + n0 + tx * 4) = o;
  }
}

// ---------------- causal depthwise conv (4 taps) + SiLU ----------------
__global__ __launch_bounds__(256) void conv_silu_kernel(
    const float* __restrict__ xz, const float* __restrict__ cw,
    const float* __restrict__ cb, float* __restrict__ xc) {
  int idx = blockIdx.x * 256 + threadIdx.x;   // over BL*DINNER
  int d = idx & (DINNER - 1);
  int bl = idx >> 10;
  int l = bl & (L_ - 1);
  float acc = cb[d];
  float w0 = cw[d * 4 + 0], w1 = cw[d * 4 + 1], w2 = cw[d * 4 + 2], w3 = cw[d * 4 + 3];
  const float* base = xz + (size_t)bl * (2 * DINNER) + d;
  if (l >= 3) acc += base[-3 * 2 * DINNER] * w0;
  if (l >= 2) acc += base[-2 * 2 * DINNER] * w1;
  if (l >= 1) acc += base[-1 * 2 * DINNER] * w2;
  acc += base[0] * w3;
  float sig = 1.f / (1.f + __expf(-acc));
  xc[idx] = acc * sig;
}

// ---------------- dt = softplus(proj[:, :32] @ W_dt^T + b_dt) ----------------
__global__ __launch_bounds__(256) void dt_kernel(
    const float* __restrict__ proj, const float* __restrict__ Wdt,
    const float* __restrict__ bdt, float* __restrict__ dt) {
  int bl = blockIdx.x >> 2;
  int d0 = (blockIdx.x & 3) * 256;
  int d = d0 + threadIdx.x;
  __shared__ float pr[DTRANK];
  __shared__ float wl[256 * 33];   // padded rows: wl[i*33 + r]
  if (threadIdx.x < DTRANK) pr[threadIdx.x] = proj[(size_t)bl * 64 + threadIdx.x];
  for (int i = threadIdx.x; i < 256 * 32; i += 256) {
    int dd = i >> 5, r = i & 31;
    wl[dd * 33 + r] = Wdt[(size_t)(d0 + dd) * 32 + r];
  }
  __syncthreads();
  float acc = bdt[d];
  const float* w = &wl[threadIdx.x * 33];
#pragma unroll
  for (int r = 0; r < 32; r++) acc += pr[r] * w[r];
  float sp = (acc > 20.f) ? acc : log1pf(__expf(acc));
  dt[(size_t)bl * DINNER + d] = sp;
}

// ---------------- scan pass 1: per-chunk decay product T and end-state E ----
__global__ __launch_bounds__(256) void scan1_kernel(
    const float* __restrict__ dt, const float* __restrict__ xc,
    const float* __restrict__ proj, const float* __restrict__ A_log,
    float* __restrict__ T, float* __restrict__ E) {
  int bid = blockIdx.x;            // 256 blocks: b(2) x c(32) x dgrp(4)
  int dgrp = bid & 3;
  int c = (bid >> 2) & (NCHUNK - 1);
  int b = bid >> 7;
  int d = dgrp * 256 + threadIdx.x;
  float Aa[16], Tn[16], En[16];
#pragma unroll
  for (int n = 0; n < 16; n++) {
    Aa[n] = -__expf(A_log[(size_t)d * 16 + n]);
    Tn[n] = 1.f; En[n] = 0.f;
  }
  int l0 = c * CLEN;
  for (int l = l0; l < l0 + CLEN; l++) {
    int bl = b * L_ + l;
    float dtv = dt[(size_t)bl * DINNER + d];
    float xv = xc[(size_t)bl * DINNER + d];
    float dx = dtv * xv;
    const float4* pB = (const float4*)(proj + (size_t)bl * 64 + 32);
    float4 b0 = pB[0], b1 = pB[1], b2 = pB[2], b3 = pB[3];
    float Bv[16] = {b0.x, b0.y, b0.z, b0.w, b1.x, b1.y, b1.z, b1.w,
                    b2.x, b2.y, b2.z, b2.w, b3.x, b3.y, b3.z, b3.w};
#pragma unroll
    for (int n = 0; n < 16; n++) {
      float dA = __expf(dtv * Aa[n]);
      Tn[n] *= dA;
      En[n] = En[n] * dA + dx * Bv[n];
    }
  }
  size_t o = (((size_t)b * NCHUNK + c) * DINNER + d) * 16;
#pragma unroll
  for (int n = 0; n < 16; n++) { T[o + n] = Tn[n]; E[o + n] = En[n]; }
}

// ---------------- sequential chunk combine: S_start written over T ----------
__global__ __launch_bounds__(256) void combine_kernel(
    float* __restrict__ T, const float* __restrict__ E) {
  int idx = blockIdx.x * 256 + threadIdx.x;   // over B*DINNER*16 = 32768
  int b = idx >> 14;
  int dn = idx & 16383;
  float s = 0.f;
  for (int c = 0; c < NCHUNK; c++) {
    size_t o = ((size_t)(b * NCHUNK + c) * (DINNER * 16)) + dn;
    float t = T[o], e = E[o];
    T[o] = s;            // S_start for this chunk
    s = t * s + e;
  }
}

// ---------------- scan pass 2: replay chunk + y + D-skip + SiLU(z) gate ----
// y is written into the xp half of xz (columns 0..1023); z read from 1024..2047
__global__ __launch_bounds__(256) void scan2_kernel(
    const float* __restrict__ dt, const float* __restrict__ xc,
    const float* __restrict__ proj, const float* __restrict__ A_log,
    const float* __restrict__ Sstart, const float* __restrict__ Dp,
    float* __restrict__ xz) {
  int bid = blockIdx.x;
  int dgrp = bid & 3;
  int c = (bid >> 2) & (NCHUNK - 1);
  int b = bid >> 7;
  int d = dgrp * 256 + threadIdx.x;
  float Aa[16], s[16];
  size_t o = (((size_t)b * NCHUNK + c) * DINNER + d) * 16;
#pragma unroll
  for (int n = 0; n < 16; n++) {
    Aa[n] = -__expf(A_log[(size_t)d * 16 + n]);
    s[n] = Sstart[o + n];
  }
  float Dv = Dp[d];
  int l0 = c * CLEN;
  for (int l = l0; l < l0 + CLEN; l++) {
    int bl = b * L_ + l;
    float dtv = dt[(size_t)bl * DINNER + d];
    float xv = xc[(size_t)bl * DINNER + d];
    float dx = dtv * xv;
    const float4* pB = (const float4*)(proj + (size_t)bl * 64 + 32);
    float4 b0 = pB[0], b1 = pB[1], b2 = pB[2], b3 = pB[3];
    const float4* pC = (const float4*)(proj + (size_t)bl * 64 + 48);
    float4 c0 = pC[0], c1 = pC[1], c2 = pC[2], c3 = pC[3];
    float Bv[16] = {b0.x, b0.y, b0.z, b0.w, b1.x, b1.y, b1.z, b1.w,
                    b2.x, b2.y, b2.z, b2.w, b3.x, b3.y, b3.z, b3.w};
    float Cv[16] = {c0.x, c0.y, c0.z, c0.w, c1.x, c1.y, c1.z, c1.w,
                    c2.x, c2.y, c2.z, c2.w, c3.x, c3.y, c3.z, c3.w};
    float y = 0.f;
#pragma unroll
    for (int n = 0; n < 16; n++) {
      float dA = __expf(dtv * Aa[n]);
      s[n] = s[n] * dA + dx * Bv[n];
      y += s[n] * Cv[n];
    }
    float zv = xz[(size_t)bl * (2 * DINNER) + DINNER + d];
    float gate = zv / (1.f + __expf(-zv));
    xz[(size_t)bl * (2 * DINNER) + d] = (y + xv * Dv) * gate;
  }
}

extern "C" void kernel_launch(void* const* d_in, const int* in_sizes, int n_in,
                              void* d_out, int out_size, void* d_ws, size_t ws_size,
                              hipStream_t stream) {
  const float* x      = (const float*)d_in[0];
  const float* ln_g   = (const float*)d_in[1];
  const float* ln_b   = (const float*)d_in[2];
  const float* W_in   = (const float*)d_in[3];
  const float* conv_w = (const float*)d_in[4];
  const float* conv_b = (const float*)d_in[5];
  const float* W_xprj = (const float*)d_in[6];
  const float* W_dt   = (const float*)d_in[7];
  const float* b_dt   = (const float*)d_in[8];
  const float* A_log  = (const float*)d_in[9];
  const float* Dp     = (const float*)d_in[10];
  const float* W_out  = (const float*)d_in[11];
  float* out = (float*)d_out;

  float* ws = (float*)d_ws;
  float* h    = ws;                               // 2,097,152
  float* xz   = h + (size_t)BL * DIM_;            // 8,388,608
  float* xc   = xz + (size_t)BL * 2 * DINNER;     // 4,194,304
  float* proj = xc + (size_t)BL * DINNER;         // 262,144
  float* dt   = proj + (size_t)BL * 64;           // 4,194,304
  float* T    = dt + (size_t)BL * DINNER;         // 1,048,576
  float* E    = T + (size_t)B_ * NCHUNK * DINNER * 16; // 1,048,576

  // 1. LayerNorm
  ln_kernel<<<BL, 64, 0, stream>>>(x, ln_g, ln_b, h);
  // 2. xz = h @ W_in^T   (M=4096, N=2048, K=512)
  gemm_tnt<false><<<dim3(2 * DINNER / 64, BL / 64), 256, 0, stream>>>(
      h, DIM_, W_in, DIM_, nullptr, 0, xz, 2 * DINNER, DIM_);
  // 3. conv + SiLU -> xc
  conv_silu_kernel<<<(BL * DINNER) / 256, 256, 0, stream>>>(xz, conv_w, conv_b, xc);
  // 4. proj = xc @ W_xproj^T (M=4096, N=64, K=1024)
  gemm_tnt<false><<<dim3(1, BL / 64), 256, 0, stream>>>(
      xc, DINNER, W_xprj, DINNER, nullptr, 0, proj, 64, DINNER);
  // 5. dt = softplus(proj[:, :32] @ W_dt^T + b_dt)
  dt_kernel<<<BL * 4, 256, 0, stream>>>(proj, W_dt, b_dt, dt);
  // 6. chunked scan
  scan1_kernel<<<B_ * NCHUNK * 4, 256, 0, stream>>>(dt, xc, proj, A_log, T, E);
  combine_kernel<<<(B_ * DINNER * 16) / 256, 256, 0, stream>>>(T, E);
  scan2_kernel<<<B_ * NCHUNK * 4, 256, 0, stream>>>(dt, xc, proj, A_log, T, Dp, xz);
  // 7. out = x + y @ W_out^T (M=4096, N=512, K=1024); y lives in xz cols 0..1023
  gemm_tnt<true><<<dim3(DIM_ / 64, BL / 64), 256, 0, stream>>>(
      xz, 2 * DINNER, W_out, DINNER, x, DIM_, out, DIM_, DINNER);
}

// Round 2
// 301.206 us; speedup vs baseline: 1.5679x; 1.5679x over previous
//
#include <hip/hip_runtime.h>
#include <hip/hip_bf16.h>
#include <math.h>

#define B_      2
#define L_      2048
#define DIM_    512
#define DINNER  1024
#define DTRANK  32
#define DSTATE  16
#define DCONV   4
#define BL      (B_ * L_)        // 4096
#define NCHUNK  32
#define CLEN    (L_ / NCHUNK)    // 64

typedef __attribute__((ext_vector_type(8))) short bf16x8;
typedef __attribute__((ext_vector_type(4))) float f32x4;

// ---------------- weight fp32->bf16 conversion (3 tensors, one launch) ------
__global__ __launch_bounds__(256) void cvt3_kernel(
    const float* __restrict__ s0, const float* __restrict__ s1,
    const float* __restrict__ s2, __hip_bfloat16* __restrict__ d0,
    __hip_bfloat16* __restrict__ d1, __hip_bfloat16* __restrict__ d2) {
  int i = (blockIdx.x * 256 + threadIdx.x) * 4;   // over 1,638,400 elems
  const float* s; __hip_bfloat16* d; int off;
  if (i < 1048576)            { s = s0; d = d0; off = i; }
  else if (i < 1048576+65536) { s = s1; d = d1; off = i - 1048576; }
  else                        { s = s2; d = d2; off = i - 1114112; }
  float4 v = *(const float4*)(s + off);
  d[off + 0] = __float2bfloat16(v.x);
  d[off + 1] = __float2bfloat16(v.y);
  d[off + 2] = __float2bfloat16(v.z);
  d[off + 3] = __float2bfloat16(v.w);
}

// ---------------- LayerNorm: one wave per row, bf16 output ----------------
__global__ __launch_bounds__(64) void ln_kernel(
    const float* __restrict__ x, const float* __restrict__ g,
    const float* __restrict__ b, __hip_bfloat16* __restrict__ h) {
  int row = blockIdx.x;
  int lane = threadIdx.x;
  const float* xr = x + (size_t)row * DIM_;
  float v[8];
  float sum = 0.f;
#pragma unroll
  for (int i = 0; i < 8; i++) { v[i] = xr[lane + i * 64]; sum += v[i]; }
#pragma unroll
  for (int o = 32; o > 0; o >>= 1) sum += __shfl_xor(sum, o, 64);
  float mu = sum * (1.f / DIM_);
  float vs = 0.f;
#pragma unroll
  for (int i = 0; i < 8; i++) { float d = v[i] - mu; vs += d * d; }
#pragma unroll
  for (int o = 32; o > 0; o >>= 1) vs += __shfl_xor(vs, o, 64);
  float rstd = rsqrtf(vs * (1.f / DIM_) + 1e-5f);
  __hip_bfloat16* hr = h + (size_t)row * DIM_;
#pragma unroll
  for (int i = 0; i < 8; i++) {
    int c = lane + i * 64;
    hr[c] = __float2bfloat16((v[i] - mu) * rstd * g[c] + b[c]);
  }
}

// ---------------- bf16 MFMA GEMM, 128x128 tile: C = A[M,K] * B[N,K]^T ------
// 256 threads = 4 waves (2x2), each wave 64x64 via 4x4 mfma_16x16x32 tiles.
// LDS rows padded to 72 shorts (144B stride -> 2-way bank alias = free).
template <bool ADD_RES>
__global__ __launch_bounds__(256) void gemm_mfma_128(
    const __hip_bfloat16* __restrict__ A, int lda,
    const __hip_bfloat16* __restrict__ Bw, int ldb,
    const float* __restrict__ Res, int ldr,
    float* __restrict__ C, int ldc, int K) {
  constexpr int LDL = 72;
  __shared__ short As[128 * LDL];
  __shared__ short Bs[128 * LDL];
  int t = threadIdx.x;
  int n0 = blockIdx.x * 128, m0 = blockIdx.y * 128;
  int w = t >> 6, lane = t & 63;
  int wm = (w >> 1) * 64, wn = (w & 1) * 64;
  int l15 = lane & 15, quad = lane >> 4;
  int srow = t >> 3, scol = (t & 7) * 8;
  const short* Ag = (const short*)A + (size_t)(m0 + srow) * lda + scol;
  const short* Bg = (const short*)Bw + (size_t)(n0 + srow) * ldb + scol;
  f32x4 acc[4][4];
#pragma unroll
  for (int i = 0; i < 4; i++)
#pragma unroll
    for (int j = 0; j < 4; j++) acc[i][j] = (f32x4){0.f, 0.f, 0.f, 0.f};
  for (int k0 = 0; k0 < K; k0 += 64) {
    __syncthreads();
#pragma unroll
    for (int p = 0; p < 4; p++) {
      *(bf16x8*)&As[(srow + p * 32) * LDL + scol] =
          *(const bf16x8*)(Ag + (size_t)(p * 32) * lda + k0);
      *(bf16x8*)&Bs[(srow + p * 32) * LDL + scol] =
          *(const bf16x8*)(Bg + (size_t)(p * 32) * ldb + k0);
    }
    __syncthreads();
#pragma unroll
    for (int kk = 0; kk < 64; kk += 32) {
      bf16x8 af[4], bfr[4];
#pragma unroll
      for (int i = 0; i < 4; i++) {
        af[i] = *(const bf16x8*)&As[(wm + i * 16 + l15) * LDL + kk + quad * 8];
        bfr[i] = *(const bf16x8*)&Bs[(wn + i * 16 + l15) * LDL + kk + quad * 8];
      }
#pragma unroll
      for (int i = 0; i < 4; i++)
#pragma unroll
        for (int j = 0; j < 4; j++)
          acc[i][j] = __builtin_amdgcn_mfma_f32_16x16x32_bf16(
              af[i], bfr[j], acc[i][j], 0, 0, 0);
    }
  }
#pragma unroll
  for (int i = 0; i < 4; i++)
#pragma unroll
    for (int r = 0; r < 4; r++) {
      int row = m0 + wm + i * 16 + quad * 4 + r;
#pragma unroll
      for (int j = 0; j < 4; j++) {
        int col = n0 + wn + j * 16 + l15;
        float v = acc[i][j][r];
        if (ADD_RES) v += Res[(size_t)row * ldr + col];
        C[(size_t)row * ldc + col] = v;
      }
    }
}

// ---------------- bf16 MFMA GEMM, 64x64 tile (for N=512 / N=64 cases) ------
template <bool ADD_RES>
__global__ __launch_bounds__(256) void gemm_mfma_64(
    const __hip_bfloat16* __restrict__ A, int lda,
    const __hip_bfloat16* __restrict__ Bw, int ldb,
    const float* __restrict__ Res, int ldr,
    float* __restrict__ C, int ldc, int K) {
  constexpr int LDL = 72;
  __shared__ short As[64 * LDL];
  __shared__ short Bs[64 * LDL];
  int t = threadIdx.x;
  int n0 = blockIdx.x * 64, m0 = blockIdx.y * 64;
  int w = t >> 6, lane = t & 63;
  int wm = (w >> 1) * 32, wn = (w & 1) * 32;
  int l15 = lane & 15, quad = lane >> 4;
  int srow = t >> 3, scol = (t & 7) * 8;
  const short* Ag = (const short*)A + (size_t)(m0 + srow) * lda + scol;
  const short* Bg = (const short*)Bw + (size_t)(n0 + srow) * ldb + scol;
  f32x4 acc[2][2];
#pragma unroll
  for (int i = 0; i < 2; i++)
#pragma unroll
    for (int j = 0; j < 2; j++) acc[i][j] = (f32x4){0.f, 0.f, 0.f, 0.f};
  for (int k0 = 0; k0 < K; k0 += 64) {
    __syncthreads();
#pragma unroll
    for (int p = 0; p < 2; p++) {
      *(bf16x8*)&As[(srow + p * 32) * LDL + scol] =
          *(const bf16x8*)(Ag + (size_t)(p * 32) * lda + k0);
      *(bf16x8*)&Bs[(srow + p * 32) * LDL + scol] =
          *(const bf16x8*)(Bg + (size_t)(p * 32) * ldb + k0);
    }
    __syncthreads();
#pragma unroll
    for (int kk = 0; kk < 64; kk += 32) {
      bf16x8 af[2], bfr[2];
#pragma unroll
      for (int i = 0; i < 2; i++) {
        af[i] = *(const bf16x8*)&As[(wm + i * 16 + l15) * LDL + kk + quad * 8];
        bfr[i] = *(const bf16x8*)&Bs[(wn + i * 16 + l15) * LDL + kk + quad * 8];
      }
#pragma unroll
      for (int i = 0; i < 2; i++)
#pragma unroll
        for (int j = 0; j < 2; j++)
          acc[i][j] = __builtin_amdgcn_mfma_f32_16x16x32_bf16(
              af[i], bfr[j], acc[i][j], 0, 0, 0);
    }
  }
#pragma unroll
  for (int i = 0; i < 2; i++)
#pragma unroll
    for (int r = 0; r < 4; r++) {
      int row = m0 + wm + i * 16 + quad * 4 + r;
#pragma unroll
      for (int j = 0; j < 2; j++) {
        int col = n0 + wn + j * 16 + l15;
        float v = acc[i][j][r];
        if (ADD_RES) v += Res[(size_t)row * ldr + col];
        C[(size_t)row * ldc + col] = v;
      }
    }
}

// ---------------- causal depthwise conv (4 taps) + SiLU; fp32 + bf16 out ---
__global__ __launch_bounds__(256) void conv_silu_kernel(
    const float* __restrict__ xz, const float* __restrict__ cw,
    const float* __restrict__ cb, float* __restrict__ xc,
    __hip_bfloat16* __restrict__ xc_bf) {
  int idx = blockIdx.x * 256 + threadIdx.x;   // over BL*DINNER
  int d = idx & (DINNER - 1);
  int bl = idx >> 10;
  int l = bl & (L_ - 1);
  float acc = cb[d];
  float w0 = cw[d * 4 + 0], w1 = cw[d * 4 + 1], w2 = cw[d * 4 + 2], w3 = cw[d * 4 + 3];
  const float* base = xz + (size_t)bl * (2 * DINNER) + d;
  if (l >= 3) acc += base[-3 * 2 * DINNER] * w0;
  if (l >= 2) acc += base[-2 * 2 * DINNER] * w1;
  if (l >= 1) acc += base[-1 * 2 * DINNER] * w2;
  acc += base[0] * w3;
  float sig = 1.f / (1.f + __expf(-acc));
  float v = acc * sig;
  xc[idx] = v;
  xc_bf[idx] = __float2bfloat16(v);
}

// ---------------- dt = softplus(proj[:, :32] @ W_dt^T + b_dt) ----------------
// 256 blocks: (BL/64 row-groups) x (4 d-groups of 256). W_dt slab in regs,
// proj rows staged in LDS (broadcast reads, conflict-free).
__global__ __launch_bounds__(256) void dt_kernel(
    const float* __restrict__ proj, const float* __restrict__ Wdt,
    const float* __restrict__ bdt, float* __restrict__ dt) {
  int blk = blockIdx.x;
  int dgrp = blk & 3;
  int bl0 = (blk >> 2) * 64;
  int d = dgrp * 256 + threadIdx.x;
  __shared__ float pr[64 * 32];
  for (int i = threadIdx.x; i < 64 * 32; i += 256) {
    int row = i >> 5, col = i & 31;
    pr[i] = proj[(size_t)(bl0 + row) * 64 + col];
  }
  float w[32];
#pragma unroll
  for (int r4 = 0; r4 < 8; r4++) {
    float4 wv = *(const float4*)(Wdt + (size_t)d * 32 + r4 * 4);
    w[r4 * 4 + 0] = wv.x; w[r4 * 4 + 1] = wv.y;
    w[r4 * 4 + 2] = wv.z; w[r4 * 4 + 3] = wv.w;
  }
  float bias = bdt[d];
  __syncthreads();
  for (int row = 0; row < 64; row++) {
    float acc = bias;
#pragma unroll
    for (int r4 = 0; r4 < 8; r4++) {
      float4 pv = *(const float4*)&pr[row * 32 + r4 * 4];
      acc += pv.x * w[r4 * 4 + 0] + pv.y * w[r4 * 4 + 1] +
             pv.z * w[r4 * 4 + 2] + pv.w * w[r4 * 4 + 3];
    }
    float sp = (acc > 20.f) ? acc : log1pf(__expf(acc));
    dt[(size_t)(bl0 + row) * DINNER + d] = sp;
  }
}

// ---------------- scan pass 1: per-chunk decay product T and end-state E ----
__global__ __launch_bounds__(256) void scan1_kernel(
    const float* __restrict__ dt, const float* __restrict__ xc,
    const float* __restrict__ proj, const float* __restrict__ A_log,
    float* __restrict__ T, float* __restrict__ E) {
  int bid = blockIdx.x;            // 256 blocks: b(2) x c(32) x dgrp(4)
  int dgrp = bid & 3;
  int c = (bid >> 2) & (NCHUNK - 1);
  int b = bid >> 7;
  int d = dgrp * 256 + threadIdx.x;
  float Aa[16], Tn[16], En[16];
#pragma unroll
  for (int n = 0; n < 16; n++) {
    Aa[n] = -__expf(A_log[(size_t)d * 16 + n]);
    Tn[n] = 1.f; En[n] = 0.f;
  }
  int l0 = c * CLEN;
  for (int l = l0; l < l0 + CLEN; l++) {
    int bl = b * L_ + l;
    float dtv = dt[(size_t)bl * DINNER + d];
    float xv = xc[(size_t)bl * DINNER + d];
    float dx = dtv * xv;
    const float4* pB = (const float4*)(proj + (size_t)bl * 64 + 32);
    float4 b0 = pB[0], b1 = pB[1], b2 = pB[2], b3 = pB[3];
    float Bv[16] = {b0.x, b0.y, b0.z, b0.w, b1.x, b1.y, b1.z, b1.w,
                    b2.x, b2.y, b2.z, b2.w, b3.x, b3.y, b3.z, b3.w};
#pragma unroll
    for (int n = 0; n < 16; n++) {
      float dA = __expf(dtv * Aa[n]);
      Tn[n] *= dA;
      En[n] = En[n] * dA + dx * Bv[n];
    }
  }
  size_t o = (((size_t)b * NCHUNK + c) * DINNER + d) * 16;
#pragma unroll
  for (int n = 0; n < 16; n++) { T[o + n] = Tn[n]; E[o + n] = En[n]; }
}

// ---------------- chunk combine: batch loads, serial math, batch stores ----
__global__ __launch_bounds__(256) void combine_kernel(
    float* __restrict__ T, const float* __restrict__ E) {
  int idx = blockIdx.x * 256 + threadIdx.x;   // over B*DINNER*16 = 32768
  int b = idx >> 14;
  int dn = idx & 16383;
  size_t base = (size_t)b * NCHUNK * (DINNER * 16) + dn;
  float t[NCHUNK], e[NCHUNK];
#pragma unroll
  for (int c = 0; c < NCHUNK; c++) {
    t[c] = T[base + (size_t)c * (DINNER * 16)];
    e[c] = E[base + (size_t)c * (DINNER * 16)];
  }
  float s = 0.f;
#pragma unroll
  for (int c = 0; c < NCHUNK; c++) {
    T[base + (size_t)c * (DINNER * 16)] = s;
    s = t[c] * s + e[c];
  }
}

// ---------------- scan pass 2: replay + y + D-skip + SiLU(z) gate ----------
// y written bf16 into the (dead) xp half of xz rows: row stride 4096 shorts.
__global__ __launch_bounds__(256) void scan2_kernel(
    const float* __restrict__ dt, const float* __restrict__ xc,
    const float* __restrict__ proj, const float* __restrict__ A_log,
    const float* __restrict__ Sstart, const float* __restrict__ Dp,
    float* __restrict__ xz) {
  int bid = blockIdx.x;
  int dgrp = bid & 3;
  int c = (bid >> 2) & (NCHUNK - 1);
  int b = bid >> 7;
  int d = dgrp * 256 + threadIdx.x;
  float Aa[16], s[16];
  size_t o = (((size_t)b * NCHUNK + c) * DINNER + d) * 16;
#pragma unroll
  for (int n = 0; n < 16; n++) {
    Aa[n] = -__expf(A_log[(size_t)d * 16 + n]);
    s[n] = Sstart[o + n];
  }
  float Dv = Dp[d];
  __hip_bfloat16* ybf = (__hip_bfloat16*)xz;
  int l0 = c * CLEN;
  for (int l = l0; l < l0 + CLEN; l++) {
    int bl = b * L_ + l;
    float dtv = dt[(size_t)bl * DINNER + d];
    float xv = xc[(size_t)bl * DINNER + d];
    float dx = dtv * xv;
    const float4* pB = (const float4*)(proj + (size_t)bl * 64 + 32);
    float4 b0 = pB[0], b1 = pB[1], b2 = pB[2], b3 = pB[3];
    const float4* pC = (const float4*)(proj + (size_t)bl * 64 + 48);
    float4 c0 = pC[0], c1 = pC[1], c2 = pC[2], c3 = pC[3];
    float Bv[16] = {b0.x, b0.y, b0.z, b0.w, b1.x, b1.y, b1.z, b1.w,
                    b2.x, b2.y, b2.z, b2.w, b3.x, b3.y, b3.z, b3.w};
    float Cv[16] = {c0.x, c0.y, c0.z, c0.w, c1.x, c1.y, c1.z, c1.w,
                    c2.x, c2.y, c2.z, c2.w, c3.x, c3.y, c3.z, c3.w};
    float y = 0.f;
#pragma unroll
    for (int n = 0; n < 16; n++) {
      float dA = __expf(dtv * Aa[n]);
      s[n] = s[n] * dA + dx * Bv[n];
      y += s[n] * Cv[n];
    }
    float zv = xz[(size_t)bl * (2 * DINNER) + DINNER + d];
    float gate = zv / (1.f + __expf(-zv));
    ybf[(size_t)bl * 4096 + d] = __float2bfloat16((y + xv * Dv) * gate);
  }
}

extern "C" void kernel_launch(void* const* d_in, const int* in_sizes, int n_in,
                              void* d_out, int out_size, void* d_ws, size_t ws_size,
                              hipStream_t stream) {
  const float* x      = (const float*)d_in[0];
  const float* ln_g   = (const float*)d_in[1];
  const float* ln_b   = (const float*)d_in[2];
  const float* W_in   = (const float*)d_in[3];
  const float* conv_w = (const float*)d_in[4];
  const float* conv_b = (const float*)d_in[5];
  const float* W_xprj = (const float*)d_in[6];
  const float* W_dt   = (const float*)d_in[7];
  const float* b_dt   = (const float*)d_in[8];
  const float* A_log  = (const float*)d_in[9];
  const float* Dp     = (const float*)d_in[10];
  const float* W_out  = (const float*)d_in[11];
  float* out = (float*)d_out;

  // workspace layout (floats) — total 84.0 MB, fits the proven-available 85 MB
  float* ws    = (float*)d_ws;
  float* xz    = ws;                       //  8,388,608 f (y_bf reuses xp half)
  float* xc    = xz + 8388608;             //  4,194,304 f
  float* R     = xc + 4194304;             //  2,097,152 f (xc_bf, then T+E)
  float* proj  = R + 2097152;              //    262,144 f
  float* dtb   = proj + 262144;            //  4,194,304 f
  float* hbf_f = dtb + 4194304;            //  1,048,576 f (h_bf: 2,097,152 bf16)
  float* wbf   = hbf_f + 1048576;          //  819,200 f (3 bf16 weight copies)

  __hip_bfloat16* xc_bf = (__hip_bfloat16*)R;
  float* T = R;
  float* E = R + 1048576;
  __hip_bfloat16* h_bf  = (__hip_bfloat16*)hbf_f;
  __hip_bfloat16* Wb_in = (__hip_bfloat16*)wbf;
  __hip_bfloat16* Wb_xp = Wb_in + 1048576;
  __hip_bfloat16* Wb_out = Wb_xp + 65536;
  __hip_bfloat16* y_bf  = (__hip_bfloat16*)xz;   // lda = 4096 shorts

  // 0. weights -> bf16
  cvt3_kernel<<<1600, 256, 0, stream>>>(W_in, W_xprj, W_out, Wb_in, Wb_xp, Wb_out);
  // 1. LayerNorm -> bf16 h
  ln_kernel<<<BL, 64, 0, stream>>>(x, ln_g, ln_b, h_bf);
  // 2. xz = h @ W_in^T   (M=4096, N=2048, K=512)  [MFMA 128x128]
  gemm_mfma_128<false><<<dim3(2 * DINNER / 128, BL / 128), 256, 0, stream>>>(
      h_bf, DIM_, Wb_in, DIM_, nullptr, 0, xz, 2 * DINNER, DIM_);
  // 3. conv + SiLU -> xc (fp32) + xc_bf (bf16)
  conv_silu_kernel<<<(BL * DINNER) / 256, 256, 0, stream>>>(xz, conv_w, conv_b, xc, xc_bf);
  // 4. proj = xc @ W_xproj^T (M=4096, N=64, K=1024)  [MFMA 64x64]
  gemm_mfma_64<false><<<dim3(1, BL / 64), 256, 0, stream>>>(
      xc_bf, DINNER, Wb_xp, DINNER, nullptr, 0, proj, 64, DINNER);
  // 5. dt = softplus(proj[:, :32] @ W_dt^T + b_dt)
  dt_kernel<<<(BL / 64) * 4, 256, 0, stream>>>(proj, W_dt, b_dt, dtb);
  // 6. chunked scan (T/E overwrite the now-dead xc_bf region)
  scan1_kernel<<<B_ * NCHUNK * 4, 256, 0, stream>>>(dtb, xc, proj, A_log, T, E);
  combine_kernel<<<(B_ * DINNER * 16) / 256, 256, 0, stream>>>(T, E);
  scan2_kernel<<<B_ * NCHUNK * 4, 256, 0, stream>>>(dtb, xc, proj, A_log, T, Dp, xz);
  // 7. out = x + y @ W_out^T (M=4096, N=512, K=1024)  [MFMA 64x64, fused res]
  gemm_mfma_64<true><<<dim3(DIM_ / 64, BL / 64), 256, 0, stream>>>(
      y_bf, 4096, Wb_out, DINNER, x, DIM_, out, DIM_, DINNER);
}